// Round 5
// baseline (196.578 us; speedup 1.0000x reference)
//
#include <hip/hip_runtime.h>
#include <hip/hip_bf16.h>
#include <cstdint>
#include <cstddef>

// Problem constants
#define CIN_K  512
#define WW_    38
#define BHW    1444          // 38*38
#define NOUT   255
#define MTOT   46208         // 32*1444 == 1444*32

#define BM     32            // m-rows per block
#define ROW_E  520           // bf16 elems per As row: 512 + 8 pad (260 dw, 260%32==4)
#define EP_DW  260           // fp32 dwords per epilogue row (32 x 260 dw = 33,280 B)

typedef __attribute__((ext_vector_type(8))) short  bf16x8;
typedef __attribute__((ext_vector_type(4))) float  floatx4;

static __device__ __forceinline__ unsigned f2bf(float f) {
    unsigned u = __builtin_bit_cast(unsigned, f);
    return (u + 0x7FFFu + ((u >> 16) & 1u)) >> 16;   // RNE to bf16
}

// RNE pack of 2 floats -> 1 dword of 2 bf16 (compiler emits v_cvt_pk_bf16_f32)
static __device__ __forceinline__ unsigned pk2bf(float a, float b) {
    __hip_bfloat162 h = __float22bfloat162_rn(make_float2(a, b));
    unsigned r;
    __builtin_memcpy(&r, &h, 4);           // bit move; bit_cast rejects non-trivial type
    return r;
}

// ---- pass 1: cw fp32 [255][512] -> wb bf16 [256][512], row 255 zeroed ----
__global__ void conv_w_to_bf16(const float* __restrict__ cw,
                               unsigned short* __restrict__ wb) {
    int tg   = blockIdx.x * 256 + threadIdx.x;   // 0..16383
    int base = tg * 8;
    int n    = base >> 9;
    unsigned rr[4] = {0u, 0u, 0u, 0u};
    if (n < NOUT) {
        float4 v0 = *(const float4*)(cw + base);
        float4 v1 = *(const float4*)(cw + base + 4);
        rr[0] = f2bf(v0.x) | (f2bf(v0.y) << 16);
        rr[1] = f2bf(v0.z) | (f2bf(v0.w) << 16);
        rr[2] = f2bf(v1.x) | (f2bf(v1.y) << 16);
        rr[3] = f2bf(v1.z) | (f2bf(v1.w) << 16);
    }
    *(uint4*)(wb + base) = *(uint4*)rr;
}

// ---- pass 2: single-stage GEMM + fused YOLO decode ----
// Block: 32 m-rows x 256 n, grid = 1444 (XCD-swizzled). Wave w: n-slice
// [w*64,+64), acc[2][4]. A staged ONCE (full K=512): 16 independent float4
// loads per thread -> deepest MLP (round-3 lesson: chunk-split/prefetch
// halved the load window and the compiler sank the prefetch at 64 VGPR).
// One barrier before compute; 16 zero-barrier K-steps; single-pass epilogue.
__global__ __launch_bounds__(256, 4)
void yolo_head(const float* __restrict__ xin,          // [32,512,38,38] fp32
               const unsigned short* __restrict__ wb,  // [256,512] bf16
               const float* __restrict__ cb,           // [255] fp32
               float* __restrict__ out)                // [46208,255] fp32
{
    __shared__ unsigned smem[BM * (ROW_E / 2)];        // 32*260 dw = 33,280 B
    unsigned short* As = (unsigned short*)smem;

    const int t    = threadIdx.x;
    const int w    = t >> 6;       // wave id -> n-slice w*64
    const int lane = t & 63;
    const int l15  = lane & 15;
    const int q    = lane >> 4;

    // bijective chunked XCD swizzle (nwg = 1444 = 8*180 + 4): contiguous
    // logical m-range per XCD -> boundary cachelines + B panel L2-hot
    // (round-3 evidence: FETCH 92 -> 48 MB).
    const int orig = blockIdx.x;
    const int xcd  = orig & 7;
    const int rank = orig >> 3;
    const int wgid = (xcd < 4 ? xcd * 181 : 724 + (xcd - 4) * 180) + rank;
    const int m0   = wgid * BM;

    // staging coords: thread owns 4m x 4k micro-tiles; 128 k per slab, 4 slabs
    const int mq4 = (t & 7) * 4;           // m-quad base within block (0..28)
    const int kq4 = (t >> 3) * 4;          // k-quad base within 128-k slab (0..124)
    const int m4  = m0 + mq4;
    const int bi  = m4 / BHW;              // never straddles b (BHW%4==0, m4%4==0)
    const int hw  = m4 - bi * BHW;
    const float* pb0 = xin + (size_t)bi * (CIN_K * BHW) + hw;

    // -------- stage: issue ALL 16 loads, then pack -> LDS ------------------
    alignas(16) float vv[4][4][4];         // [slab][kk][m]
#pragma unroll
    for (int it = 0; it < 4; ++it)
#pragma unroll
        for (int kk = 0; kk < 4; ++kk)
            *(float4*)&vv[it][kk][0] =
                *(const float4*)(pb0 + (size_t)(it * 128 + kq4 + kk) * BHW);
#pragma unroll
    for (int it = 0; it < 4; ++it)
#pragma unroll
        for (int r = 0; r < 4; ++r) {
            unsigned lo = pk2bf(vv[it][0][r], vv[it][1][r]);
            unsigned hi = pk2bf(vv[it][2][r], vv[it][3][r]);
            *(uint2*)(&As[(mq4 + r) * ROW_E + it * 128 + kq4]) = make_uint2(lo, hi);
        }

    floatx4 acc[2][4];
#pragma unroll
    for (int i = 0; i < 2; ++i)
#pragma unroll
        for (int j = 0; j < 4; ++j)
            acc[i][j] = (floatx4){0.f, 0.f, 0.f, 0.f};

    // B frag addr: n = w*64 + j*16 + l15, k = kc*32 + q*8
    const unsigned short* pbw = wb + (size_t)(w * 64 + l15) * CIN_K + q * 8;

    __syncthreads();     // the ONLY barrier before the K-loop

    // -------- hot loop: 16 K-steps, ZERO barriers --------------------------
#pragma unroll
    for (int kc = 0; kc < 16; ++kc) {
        bf16x8 bfr[4], af[2];
#pragma unroll
        for (int j = 0; j < 4; ++j) {
            uint4 bv = *(const uint4*)(pbw + (size_t)j * 16 * CIN_K + kc * 32);
            bfr[j] = __builtin_bit_cast(bf16x8, bv);
        }
#pragma unroll
        for (int i = 0; i < 2; ++i) {
            int4 av = *(const int4*)(&As[(i * 16 + l15) * ROW_E + kc * 32 + q * 8]);
            af[i] = __builtin_bit_cast(bf16x8, av);
        }
#pragma unroll
        for (int i = 0; i < 2; ++i)
#pragma unroll
            for (int j = 0; j < 4; ++j)
                acc[i][j] = __builtin_amdgcn_mfma_f32_16x16x32_bf16(
                                af[i], bfr[j], acc[i][j], 0, 0, 0);
    }

    // -------- fused YOLO decode (in place on acc) --------------------------
    // C/D layout: col(n) = l15 (+16j), row(m) = i*16 + q*4 + r
#pragma unroll
    for (int j = 0; j < 4; ++j) {
        int   n    = w * 64 + j * 16 + l15;
        int   nc   = n < NOUT ? n : NOUT - 1;
        int   ai   = nc / 85;
        int   ji   = nc - ai * 85;
        float bias = cb[nc];
        float aw   = (ai == 0) ? 30.f : (ai == 1) ? 62.f : 59.f;
        float ah   = (ai == 0) ? 61.f : (ai == 1) ? 45.f : 119.f;
#pragma unroll
        for (int i = 0; i < 2; ++i)
#pragma unroll
            for (int r = 0; r < 4; ++r) {
                int   md  = m0 + i * 16 + q * 4 + r;
                int   rem = md % BHW;
                int   hh  = rem / WW_;
                float v   = acc[i][j][r] + bias;
                float res;
                if (ji == 0)      res = (1.f / (1.f + __expf(-v)) + (float)(rem - hh * WW_)) * 16.f;
                else if (ji == 1) res = (1.f / (1.f + __expf(-v)) + (float)hh) * 16.f;
                else if (ji == 2) res = __expf(v) * aw;
                else if (ji == 3) res = __expf(v) * ah;
                else              res = v;
                acc[i][j][r] = res;
            }
    }

    // -------- epilogue: single-pass LDS transpose + aligned stores ---------
    __syncthreads();                       // all As readers done; reuse as EP[32][260]
    float* EP = (float*)smem;
#pragma unroll
    for (int i = 0; i < 2; ++i)
#pragma unroll
        for (int j = 0; j < 4; ++j)
#pragma unroll
            for (int r = 0; r < 4; ++r)
                EP[(i * 16 + q * 4 + r) * EP_DW + w * 64 + j * 16 + l15] =
                    acc[i][j][r];
    __syncthreads();

    // wave w stores rows [w*8, w*8+8): 8*255 = 2040 floats, 16B-aligned base
    {
        const float* EPb = (const float*)smem + (w * 8) * EP_DW;
        float*       ob  = out + (size_t)(m0 + w * 8) * NOUT;
#pragma unroll
        for (int s2 = 0; s2 < 8; ++s2) {
            int f4 = s2 * 64 + lane;       // float4 index, 0..509
            if (f4 < 510) {
                int   f = f4 * 4;
                float vs[4];
#pragma unroll
                for (int e = 0; e < 4; ++e) {
                    int fe = f + e;
                    int mr = fe / NOUT;
                    int x  = fe - mr * NOUT;
                    vs[e]  = EPb[mr * EP_DW + x];
                }
                *(float4*)(ob + f) = make_float4(vs[0], vs[1], vs[2], vs[3]);
            }
        }
    }
}

extern "C" void kernel_launch(void* const* d_in, const int* in_sizes, int n_in,
                              void* d_out, int out_size, void* d_ws, size_t ws_size,
                              hipStream_t stream) {
    const float* xin = (const float*)d_in[0];
    const float* cw  = (const float*)d_in[1];
    const float* cb  = (const float*)d_in[2];
    float*       out = (float*)d_out;
    unsigned short* wb = (unsigned short*)d_ws;   // 256*512*2 = 256 KiB

    hipLaunchKernelGGL(conv_w_to_bf16, dim3(64), dim3(256), 0, stream, cw, wb);
    hipLaunchKernelGGL(yolo_head, dim3(MTOT / BM), dim3(256), 0, stream,
                       xin, wb, cb, out);
}

// Round 6
// 192.567 us; speedup vs baseline: 1.0208x; 1.0208x over previous
//
#include <hip/hip_runtime.h>
#include <hip/hip_bf16.h>
#include <cstdint>
#include <cstddef>

// Problem constants
#define CIN_K  512
#define WW_    38
#define BHW    1444          // 38*38
#define NOUT   255
#define MTOT   46208         // 32*1444 == 722*64

#define BM     64            // m-rows per block (R1 winner: halves B-panel re-reads)
#define KCH    256           // K elems staged per chunk (2 chunks of 256)
#define ROW_E  260           // bf16 elems per As row: 256 + 4 pad (130 dw, 130%32==2)

typedef __attribute__((ext_vector_type(8))) short  bf16x8;
typedef __attribute__((ext_vector_type(4))) float  floatx4;

static __device__ __forceinline__ unsigned f2bf(float f) {
    unsigned u = __builtin_bit_cast(unsigned, f);
    return (u + 0x7FFFu + ((u >> 16) & 1u)) >> 16;   // RNE to bf16
}

// RNE pack of 2 floats -> 1 dword of 2 bf16 (compiler emits v_cvt_pk_bf16_f32)
static __device__ __forceinline__ unsigned pk2bf(float a, float b) {
    __hip_bfloat162 h = __float22bfloat162_rn(make_float2(a, b));
    unsigned r;
    __builtin_memcpy(&r, &h, 4);           // bit move; bit_cast rejects non-trivial type
    return r;
}

// ---- pass 1: cw fp32 [255][512] -> wb bf16 [256][512], row 255 zeroed ----
__global__ void conv_w_to_bf16(const float* __restrict__ cw,
                               unsigned short* __restrict__ wb) {
    int tg   = blockIdx.x * 256 + threadIdx.x;   // 0..16383
    int base = tg * 8;
    int n    = base >> 9;
    unsigned rr[4] = {0u, 0u, 0u, 0u};
    if (n < NOUT) {
        float4 v0 = *(const float4*)(cw + base);
        float4 v1 = *(const float4*)(cw + base + 4);
        rr[0] = f2bf(v0.x) | (f2bf(v0.y) << 16);
        rr[1] = f2bf(v0.z) | (f2bf(v0.w) << 16);
        rr[2] = f2bf(v1.x) | (f2bf(v1.y) << 16);
        rr[3] = f2bf(v1.z) | (f2bf(v1.w) << 16);
    }
    *(uint4*)(wb + base) = *(uint4*)rr;
}

// ---- pass 2: K-chunked GEMM + fused YOLO decode, direct-store epilogue ----
// EXACT R1 structure (71 us: BM=64, 2 K-chunks of 256, LDS 33,280 B -> 4
// blocks/CU), minus the LDS epilogue: decode writes straight from acc with
// scalar stores (each instr = 4 x 64-B aligned segments). Removes 2 barriers,
// 128 LDS ops, 1.27M bank conflicts. Packing via v_cvt_pk_bf16_f32.
__global__ __launch_bounds__(256, 4)
void yolo_head(const float* __restrict__ xin,          // [32,512,38,38] fp32
               const unsigned short* __restrict__ wb,  // [256,512] bf16
               const float* __restrict__ cb,           // [255] fp32
               float* __restrict__ out)                // [46208,255] fp32
{
    __shared__ unsigned smem[BM * (ROW_E / 2)];        // 64*130 dw = 33,280 B
    unsigned short* As = (unsigned short*)smem;

    const int t    = threadIdx.x;
    const int w    = t >> 6;       // wave id -> n-slice w*64
    const int lane = t & 63;
    const int l15  = lane & 15;
    const int q    = lane >> 4;

    // bijective chunked XCD swizzle: nwg = 722 = 8*90 + 2 (q=90, r=2).
    // Contiguous logical m-range per XCD -> B panel + boundary lines L2-hot.
    const int orig = blockIdx.x;
    const int xcd  = orig & 7;
    const int rank = orig >> 3;
    const int wgid = (xcd < 2 ? xcd * 91 : 182 + (xcd - 2) * 90) + rank;
    const int m0   = wgid * BM;

    // staging coords: thread owns 4m x 4k micro-tiles; 64 k per slab, 4 slabs
    const int mq4 = (t & 15) * 4;          // m-quad base within block (0..60)
    const int kq4 = (t >> 4) * 4;          // k-quad base within 64-k slab (0..60)
    const int m4  = m0 + mq4;
    const int bi  = m4 / BHW;              // never straddles b (BHW%4==0, m4%4==0)
    const int hw  = m4 - bi * BHW;
    const float* pb0 = xin + (size_t)bi * (CIN_K * BHW) + hw;

    floatx4 acc[4][4];
#pragma unroll
    for (int i = 0; i < 4; ++i)
#pragma unroll
        for (int j = 0; j < 4; ++j)
            acc[i][j] = (floatx4){0.f, 0.f, 0.f, 0.f};

    // B frag addr: n = w*64 + j*16 + l15, k = ck*256 + kc*32 + q*8
    const unsigned short* pbw = wb + (size_t)(w * 64 + l15) * CIN_K + q * 8;

#pragma unroll
    for (int ck = 0; ck < 2; ++ck) {
        if (ck) __syncthreads();           // all readers of previous chunk done

        // -------- stage chunk ck: 64 m x 256 k fp32 -> bf16 in LDS ----------
#pragma unroll
        for (int it = 0; it < 4; ++it) {   // 4 slabs of 64 k
            const int kl = it * 64 + kq4;  // k local to chunk (0..252, mult of 4)
            alignas(16) float vv[4][4];
#pragma unroll
            for (int kk = 0; kk < 4; ++kk)
                *(float4*)&vv[kk][0] =
                    *(const float4*)(pb0 + (size_t)(ck * KCH + kl + kk) * BHW);
            // in-register 4x4 transpose: pack 4 k for each of 4 m
#pragma unroll
            for (int r = 0; r < 4; ++r) {
                unsigned lo = pk2bf(vv[0][r], vv[1][r]);
                unsigned hi = pk2bf(vv[2][r], vv[3][r]);
                *(uint2*)(&As[(mq4 + r) * ROW_E + kl]) = make_uint2(lo, hi);
            }
        }
        __syncthreads();

        // -------- compute 8 K-steps on this chunk ---------------------------
#pragma unroll
        for (int kc = 0; kc < 8; ++kc) {
            bf16x8 bfr[4], af[4];
#pragma unroll
            for (int j = 0; j < 4; ++j) {
                uint4 bv = *(const uint4*)(pbw + (size_t)j * 16 * CIN_K
                                           + ck * KCH + kc * 32);
                bfr[j] = __builtin_bit_cast(bf16x8, bv);
            }
#pragma unroll
            for (int i = 0; i < 4; ++i) {
                int4 av = *(const int4*)(&As[(i * 16 + l15) * ROW_E + kc * 32 + q * 8]);
                af[i] = __builtin_bit_cast(bf16x8, av);
            }
#pragma unroll
            for (int i = 0; i < 4; ++i)
#pragma unroll
                for (int j = 0; j < 4; ++j)
                    acc[i][j] = __builtin_amdgcn_mfma_f32_16x16x32_bf16(
                                    af[i], bfr[j], acc[i][j], 0, 0, 0);
        }
    }

    // -------- fused YOLO decode + DIRECT global stores ---------------------
    // C/D layout: col(n) = l15 (+16j), row(m) = i*16 + q*4 + r.
    // Per store instr: lanes span 16 consecutive n (64-B aligned) x 4 m-rows.
#pragma unroll
    for (int j = 0; j < 4; ++j) {
        int   n    = w * 64 + j * 16 + l15;
        bool  ok   = n < NOUT;             // false only for w=3,j=3,l15=15
        int   nc   = ok ? n : NOUT - 1;
        int   ai   = nc / 85;
        int   ji   = nc - ai * 85;
        float bias = cb[nc];
        float aw   = (ai == 0) ? 30.f : (ai == 1) ? 62.f : 59.f;
        float ah   = (ai == 0) ? 61.f : (ai == 1) ? 45.f : 119.f;
#pragma unroll
        for (int i = 0; i < 4; ++i)
#pragma unroll
            for (int r = 0; r < 4; ++r) {
                int   md  = m0 + i * 16 + q * 4 + r;
                int   rem = md % BHW;
                int   hh  = rem / WW_;
                float v   = acc[i][j][r] + bias;
                float res;
                if (ji == 0)      res = (1.f / (1.f + __expf(-v)) + (float)(rem - hh * WW_)) * 16.f;
                else if (ji == 1) res = (1.f / (1.f + __expf(-v)) + (float)hh) * 16.f;
                else if (ji == 2) res = __expf(v) * aw;
                else if (ji == 3) res = __expf(v) * ah;
                else              res = v;
                if (ok) out[(size_t)md * NOUT + n] = res;
            }
    }
}

extern "C" void kernel_launch(void* const* d_in, const int* in_sizes, int n_in,
                              void* d_out, int out_size, void* d_ws, size_t ws_size,
                              hipStream_t stream) {
    const float* xin = (const float*)d_in[0];
    const float* cw  = (const float*)d_in[1];
    const float* cb  = (const float*)d_in[2];
    float*       out = (float*)d_out;
    unsigned short* wb = (unsigned short*)d_ws;   // 256*512*2 = 256 KiB

    hipLaunchKernelGGL(conv_w_to_bf16, dim3(64), dim3(256), 0, stream, cw, wb);
    hipLaunchKernelGGL(yolo_head, dim3(MTOT / BM), dim3(256), 0, stream,
                       xin, wb, cb, out);
}